// Round 1
// baseline (4526.351 us; speedup 1.0000x reference)
//
#include <hip/hip_runtime.h>

#define DEV __device__ __forceinline__

typedef __attribute__((ext_vector_type(8))) short short8;
typedef __attribute__((ext_vector_type(4))) float floatx4;

static constexpr int B_ = 512, T_ = 912, H_ = 128, F_ = 32;
static constexpr int RING = 64;                       // ring slots per layer boundary
static constexpr size_t HN_OFF   = 1024;              // bf16 hN[4][512][128]
static constexpr size_t XT_OFF   = HN_OFF + (size_t)4 * 512 * 128 * 2;        // 525312
static constexpr size_t RING_OFF = XT_OFF + (size_t)T_ * B_ * F_ * 2;         // 30409728
static constexpr size_t RING_ELEMS = (size_t)RING * B_ * H_;                  // 4194304

DEV unsigned short bf16rne(float f) {
    unsigned u = __builtin_bit_cast(unsigned, f);
    u += 0x7FFFu + ((u >> 16) & 1u);
    return (unsigned short)(u >> 16);
}
DEV float bf16tof(unsigned short u) {
    return __builtin_bit_cast(float, ((unsigned)u) << 16);
}
DEV float sigm(float x) {
    return __builtin_amdgcn_rcpf(1.f + __builtin_amdgcn_exp2f(-1.44269504f * x));
}
DEV float tanh_(float x) {
    return 2.f * __builtin_amdgcn_rcpf(1.f + __builtin_amdgcn_exp2f(-2.88539008f * x)) - 1.f;
}

// ---------------------------------------------------------------------------
// x [B][T][32] fp32  ->  xT [T][B][32] bf16
__global__ __launch_bounds__(256) void xpose(const float* __restrict__ x,
                                             unsigned short* __restrict__ xT) {
    int tid = blockIdx.x * 256 + threadIdx.x;          // 512*912*4 threads
    if (tid >= B_ * T_ * 4) return;
    int k = tid & 3;
    int r = tid >> 2;                                  // r = b*912 + t
    int b = r / T_;
    int t = r - b * T_;
    const float* p = x + ((size_t)r * 32 + k * 8);
    short8 v;
#pragma unroll
    for (int j = 0; j < 8; j++) v[j] = (short)bf16rne(p[j]);
    *(short8*)(xT + ((size_t)t * 512 + b) * 32 + k * 8) = v;
}

// ---------------------------------------------------------------------------
// Pipelined 4-layer LSTM scan.
// 128 blocks = 4 layers x 32 groups (16 samples each). block = 32*layer+grp
// so producer/consumer of a group share blockIdx%8 (same-XCD heuristic).
// 8 waves/block; wave w owns h-cols [16w,16w+16) across all 4 gates.
__global__ __launch_bounds__(512) void lstm_scan(
    const float* __restrict__ Wih0, const float* __restrict__ Whh0,
    const float* __restrict__ bih0, const float* __restrict__ bhh0,
    const float* __restrict__ Wih123, const float* __restrict__ Whh123,
    const float* __restrict__ bih123, const float* __restrict__ bhh123,
    char* __restrict__ ws) {
    const int tid  = threadIdx.x;
    const int wv   = tid >> 6;     // 0..7
    const int lane = tid & 63;
    const int col  = lane & 15;    // N / M index inside a 16-tile
    const int quad = lane >> 4;    // k-chunk selector
    const int blk  = blockIdx.x;
    const int layer = blk >> 5;
    const int grp   = blk & 31;
    const int b0    = grp * 16;

    unsigned* flags = (unsigned*)ws;                   // [4][32] producer progress
    unsigned* cons  = (unsigned*)(ws + 512);           // [4][32] consumer progress
    unsigned short* hN   = (unsigned short*)(ws + HN_OFF);
    unsigned short* xT   = (unsigned short*)(ws + XT_OFF);
    unsigned short* ring = (unsigned short*)(ws + RING_OFF);

    __shared__ unsigned short Ah[2][16][136];          // padded stride: 272B = 17*16B

    for (int i = tid; i < 16 * 136; i += 512) ((unsigned short*)Ah[0])[i] = 0;

    // ---- load persistent weight fragments (bf16) ------------------------
    // B-fragment for tile (gate q, ktile kt): lane holds W[row][kt*32+quad*8 .. +8)
    // row = q*128 + 16*wv + col  (wave w owns h-cols 16w..16w+16 of every gate)
    short8 wh[4][4];   // recurrent part, K = 128
    short8 wx[4][4];   // input part, K = 32 (layer0, kt=0 only) or 128
    float  bias_q[4];
    const int KX = (layer == 0) ? 1 : 4;
    {
        const float *Wih, *Whh, *bih, *bhh;
        int kin;
        if (layer == 0) { Wih = Wih0; Whh = Whh0; bih = bih0; bhh = bhh0; kin = 32; }
        else {
            Wih = Wih123 + (size_t)(layer - 1) * 512 * 128;
            Whh = Whh123 + (size_t)(layer - 1) * 512 * 128;
            bih = bih123 + (size_t)(layer - 1) * 512;
            bhh = bhh123 + (size_t)(layer - 1) * 512;
            kin = 128;
        }
#pragma unroll
        for (int q = 0; q < 4; q++) {
            int row = q * 128 + wv * 16 + col;
            bias_q[q] = bih[row] + bhh[row];
#pragma unroll
            for (int kt = 0; kt < 4; kt++) {
                const float* ph = Whh + (size_t)row * 128 + kt * 32 + quad * 8;
                short8 v;
#pragma unroll
                for (int j = 0; j < 8; j++) v[j] = (short)bf16rne(ph[j]);
                wh[q][kt] = v;
            }
#pragma unroll
            for (int kt = 0; kt < 4; kt++) {
                short8 v = {0, 0, 0, 0, 0, 0, 0, 0};
                if (kt < KX) {
                    const float* px = Wih + (size_t)row * kin + kt * 32 + quad * 8;
#pragma unroll
                    for (int j = 0; j < 8; j++) v[j] = (short)bf16rne(px[j]);
                }
                wx[q][kt] = v;
            }
        }
    }

    unsigned* myflag   = &flags[layer * 32 + grp];
    unsigned* prevflag = (layer > 0) ? &flags[(layer - 1) * 32 + grp] : nullptr;
    unsigned* mycons   = (layer > 0) ? &cons[(layer - 1) * 32 + grp] : nullptr;
    unsigned* nextcons = (layer < 3) ? &cons[layer * 32 + grp] : nullptr;

    const unsigned short* xsrc0 = (layer == 0)
        ? xT : (ring + (size_t)(layer - 1) * RING_ELEMS);
    unsigned short* mring = (layer < 3) ? (ring + (size_t)layer * RING_ELEMS) : nullptr;

    float c4[4] = {0.f, 0.f, 0.f, 0.f};
    const int hcol = wv * 16 + col;

    for (int t = 0; t < T_; ++t) {
        // ---- control phase (different waves so spins overlap) ----------
        if (tid == 64 && layer > 0)
            __hip_atomic_store(mycons, (unsigned)t, __ATOMIC_RELAXED, __HIP_MEMORY_SCOPE_AGENT);
        if (tid == 128 && layer < 3) {                 // ring back-pressure
            while ((int)t - (int)__hip_atomic_load(nextcons, __ATOMIC_RELAXED,
                                                   __HIP_MEMORY_SCOPE_AGENT) >= RING) {}
        }
        if (tid == 192 && layer > 0) {                 // wait for producer step t
            while (__hip_atomic_load(prevflag, __ATOMIC_ACQUIRE,
                                     __HIP_MEMORY_SCOPE_AGENT) < (unsigned)(t + 1)) {}
        }
        __syncthreads();   // A: control done, prev-step Ah writes done

        const int slot = t & (RING - 1);
        // ---- x-part A fragments (global) --------------------------------
        short8 ax[4];
        if (layer == 0) {
            const unsigned short* p = xsrc0 + ((size_t)t * 512 + b0 + col) * 32 + quad * 8;
            ax[0] = *(const short8*)p;
        } else {
            const unsigned short* p = xsrc0 + ((size_t)slot * 512 + b0 + col) * 128 + quad * 8;
#pragma unroll
            for (int kt = 0; kt < 4; kt++) ax[kt] = *(const short8*)(p + kt * 32);
        }
        // ---- h-part A fragments (LDS) -----------------------------------
        const int rb = t & 1;
        short8 ah[4];
        {
            const unsigned short* base = &Ah[rb][col][quad * 8];
#pragma unroll
            for (int kt = 0; kt < 4; kt++) ah[kt] = *(const short8*)(base + kt * 32);
        }
        floatx4 acc[4];
#pragma unroll
        for (int q = 0; q < 4; q++) {
            float bq = bias_q[q];
            floatx4 a = {bq, bq, bq, bq};
            acc[q] = a;
        }
        // recurrent part first (LDS data ready; global x loads still in flight)
#pragma unroll
        for (int kt = 0; kt < 4; kt++)
#pragma unroll
            for (int q = 0; q < 4; q++)
                acc[q] = __builtin_amdgcn_mfma_f32_16x16x32_bf16(ah[kt], wh[q][kt], acc[q], 0, 0, 0);
        if (layer == 0) {
#pragma unroll
            for (int q = 0; q < 4; q++)
                acc[q] = __builtin_amdgcn_mfma_f32_16x16x32_bf16(ax[0], wx[q][0], acc[q], 0, 0, 0);
        } else {
#pragma unroll
            for (int kt = 0; kt < 4; kt++)
#pragma unroll
                for (int q = 0; q < 4; q++)
                    acc[q] = __builtin_amdgcn_mfma_f32_16x16x32_bf16(ax[kt], wx[q][kt], acc[q], 0, 0, 0);
        }
        // ---- gates + state update --------------------------------------
        // acc reg r of tile q: sample m = quad*4+r, gate-col = hcol
#pragma unroll
        for (int r = 0; r < 4; r++) {
            float iv = sigm(acc[0][r]);
            float fv = sigm(acc[1][r]);
            float gv = tanh_(acc[2][r]);
            float ov = sigm(acc[3][r]);
            float cv = fv * c4[r] + iv * gv;
            c4[r] = cv;
            float hv = ov * tanh_(cv);
            unsigned short hb = bf16rne(hv);
            int m = quad * 4 + r;
            Ah[1 - rb][m][hcol] = hb;
            if (layer < 3)
                mring[((size_t)slot * 512 + b0 + m) * 128 + hcol] = hb;
            if (t == T_ - 1)
                hN[((size_t)layer * 512 + b0 + m) * 128 + hcol] = hb;
        }
        __syncthreads();   // B: all stores drained (vmcnt(0) before s_barrier)
        if (tid == 0 && layer < 3) {
            __threadfence();                            // agent release (L2 wb)
            __hip_atomic_store(myflag, (unsigned)(t + 1), __ATOMIC_RELAXED,
                               __HIP_MEMORY_SCOPE_AGENT);
        }
    }
}

// ---------------------------------------------------------------------------
// heads: hN [4][512][128] bf16 -> opt/tp/sl/lot, each [4][512][4] fp32
__global__ __launch_bounds__(256) void heads(
    const unsigned short* __restrict__ hN,
    const float* __restrict__ Wopt, const float* __restrict__ bopt,
    const float* __restrict__ Wlot, const float* __restrict__ blot,
    const float* __restrict__ Wtp,  const float* __restrict__ btp,
    const float* __restrict__ Wsl,  const float* __restrict__ bsl,
    float* __restrict__ out) {
    int tid = blockIdx.x * 256 + threadIdx.x;          // 8192
    if (tid >= 4 * 4 * 512) return;
    int b  = tid & 511;
    int l  = (tid >> 9) & 3;
    int hd = tid >> 11;                                // 0 opt, 1 tp, 2 sl, 3 lot
    const float *W, *bb;
    if      (hd == 0) { W = Wopt; bb = bopt; }
    else if (hd == 1) { W = Wtp;  bb = btp;  }
    else if (hd == 2) { W = Wsl;  bb = bsl;  }
    else              { W = Wlot; bb = blot; }
    const unsigned short* h = hN + ((size_t)l * 512 + b) * 128;
    float z0 = bb[0], z1 = bb[1], z2 = bb[2], z3 = bb[3];
    for (int i = 0; i < 128; i++) {
        float hv = bf16tof(h[i]);
        z0 += hv * W[0 * 128 + i];
        z1 += hv * W[1 * 128 + i];
        z2 += hv * W[2 * 128 + i];
        z3 += hv * W[3 * 128 + i];
    }
    float o0, o1, o2, o3;
    if (hd == 0) {
        // softmax applied twice
        float m = fmaxf(fmaxf(z0, z1), fmaxf(z2, z3));
        float e0 = __builtin_amdgcn_exp2f((z0 - m) * 1.44269504f);
        float e1 = __builtin_amdgcn_exp2f((z1 - m) * 1.44269504f);
        float e2 = __builtin_amdgcn_exp2f((z2 - m) * 1.44269504f);
        float e3 = __builtin_amdgcn_exp2f((z3 - m) * 1.44269504f);
        float rs = __builtin_amdgcn_rcpf(e0 + e1 + e2 + e3);
        float p0 = e0 * rs, p1 = e1 * rs, p2 = e2 * rs, p3 = e3 * rs;
        float m2 = fmaxf(fmaxf(p0, p1), fmaxf(p2, p3));
        float f0 = __builtin_amdgcn_exp2f((p0 - m2) * 1.44269504f);
        float f1 = __builtin_amdgcn_exp2f((p1 - m2) * 1.44269504f);
        float f2 = __builtin_amdgcn_exp2f((p2 - m2) * 1.44269504f);
        float f3 = __builtin_amdgcn_exp2f((p3 - m2) * 1.44269504f);
        float rs2 = __builtin_amdgcn_rcpf(f0 + f1 + f2 + f3);
        o0 = f0 * rs2; o1 = f1 * rs2; o2 = f2 * rs2; o3 = f3 * rs2;
    } else {
        o0 = sigm(sigm(z0)); o1 = sigm(sigm(z1));
        o2 = sigm(sigm(z2)); o3 = sigm(sigm(z3));
    }
    float* o = out + (size_t)hd * 8192 + ((size_t)l * 512 + b) * 4;
    o[0] = o0; o[1] = o1; o[2] = o2; o[3] = o3;
}

// ---------------------------------------------------------------------------
extern "C" void kernel_launch(void* const* d_in, const int* in_sizes, int n_in,
                              void* d_out, int out_size, void* d_ws, size_t ws_size,
                              hipStream_t stream) {
    (void)in_sizes; (void)n_in; (void)out_size; (void)ws_size;
    const float* x      = (const float*)d_in[0];
    const float* Wih0   = (const float*)d_in[1];
    const float* Whh0   = (const float*)d_in[2];
    const float* bih0   = (const float*)d_in[3];
    const float* bhh0   = (const float*)d_in[4];
    const float* Wih123 = (const float*)d_in[5];
    const float* Whh123 = (const float*)d_in[6];
    const float* bih123 = (const float*)d_in[7];
    const float* bhh123 = (const float*)d_in[8];
    const float* Wopt = (const float*)d_in[9];
    const float* bopt = (const float*)d_in[10];
    const float* Wlot = (const float*)d_in[11];
    const float* blot = (const float*)d_in[12];
    const float* Wtp  = (const float*)d_in[13];
    const float* btp  = (const float*)d_in[14];
    const float* Wsl  = (const float*)d_in[15];
    const float* bsl  = (const float*)d_in[16];
    char* ws = (char*)d_ws;

    hipMemsetAsync(ws, 0, 1024, stream);               // flags + cons
    xpose<<<(B_ * T_ * 4 + 255) / 256, 256, 0, stream>>>(x, (unsigned short*)(ws + XT_OFF));
    lstm_scan<<<128, 512, 0, stream>>>(Wih0, Whh0, bih0, bhh0,
                                       Wih123, Whh123, bih123, bhh123, ws);
    heads<<<32, 256, 0, stream>>>((const unsigned short*)(ws + HN_OFF),
                                  Wopt, bopt, Wlot, blot, Wtp, btp, Wsl, bsl,
                                  (float*)d_out);
}

// Round 2
// 2311.094 us; speedup vs baseline: 1.9585x; 1.9585x over previous
//
#include <hip/hip_runtime.h>

#define DEV __device__ __forceinline__

typedef __attribute__((ext_vector_type(8))) short short8;
typedef __attribute__((ext_vector_type(4))) float floatx4;
typedef unsigned long long ull;

static constexpr int B_ = 512, T_ = 912, H_ = 128, F_ = 32;
static constexpr int RING = 64;                       // ring slots per layer boundary
static constexpr size_t HN_OFF   = 1024;              // bf16 hN[4][512][128]
static constexpr size_t XT_OFF   = HN_OFF + (size_t)4 * 512 * 128 * 2;
static constexpr size_t RING_OFF = XT_OFF + (size_t)T_ * B_ * F_ * 2;
// ring: [3 boundaries][32 groups][64 slots][16 b][128 k] bf16 -> qwords (8B = 4 bf16)
static constexpr size_t RING_QW_PER_GRP = (size_t)RING * 16 * 128 / 4;   // 32768 qwords

DEV unsigned short bf16rne(float f) {
    unsigned u = __builtin_bit_cast(unsigned, f);
    u += 0x7FFFu + ((u >> 16) & 1u);
    return (unsigned short)(u >> 16);
}
DEV float bf16tof(unsigned short u) {
    return __builtin_bit_cast(float, ((unsigned)u) << 16);
}
DEV float sigm(float x) {
    return __builtin_amdgcn_rcpf(1.f + __builtin_amdgcn_exp2f(-1.44269504f * x));
}
DEV float tanh_(float x) {
    return 2.f * __builtin_amdgcn_rcpf(1.f + __builtin_amdgcn_exp2f(-2.88539008f * x)) - 1.f;
}

// ---------------------------------------------------------------------------
// x [B][T][32] fp32  ->  xT [T][B][32] bf16
__global__ __launch_bounds__(256) void xpose(const float* __restrict__ x,
                                             unsigned short* __restrict__ xT) {
    int tid = blockIdx.x * 256 + threadIdx.x;
    if (tid >= B_ * T_ * 4) return;
    int k = tid & 3;
    int r = tid >> 2;                                  // r = b*912 + t
    int b = r / T_;
    int t = r - b * T_;
    const float* p = x + ((size_t)r * 32 + k * 8);
    short8 v;
#pragma unroll
    for (int j = 0; j < 8; j++) v[j] = (short)bf16rne(p[j]);
    *(short8*)(xT + ((size_t)t * 512 + b) * 32 + k * 8) = v;
}

// ---------------------------------------------------------------------------
// Pipelined 4-layer LSTM scan. 128 blocks = 4 layers x 32 groups (16 samples).
// Inter-layer h goes through a MALL-resident ring via RELAXED agent-scope
// 8B atomics (sc1 path) -- NO fences, NO L2 writeback/invalidate.
// Release ordering: __syncthreads() drains vmcnt(0); flag stored after it.
__global__ __launch_bounds__(512, 2) void lstm_scan(
    const float* __restrict__ Wih0, const float* __restrict__ Whh0,
    const float* __restrict__ bih0, const float* __restrict__ bhh0,
    const float* __restrict__ Wih123, const float* __restrict__ Whh123,
    const float* __restrict__ bih123, const float* __restrict__ bhh123,
    char* __restrict__ ws) {
    const int tid  = threadIdx.x;
    const int wv   = tid >> 6;     // 0..7
    const int lane = tid & 63;
    const int col  = lane & 15;
    const int quad = lane >> 4;
    const int blk  = blockIdx.x;
    const int layer = blk >> 5;
    const int grp   = blk & 31;
    const int b0    = grp * 16;

    unsigned* flags = (unsigned*)ws;                   // [4][32] producer progress
    unsigned* cons  = (unsigned*)(ws + 512);           // [4][32] consumer progress
    unsigned short* hN = (unsigned short*)(ws + HN_OFF);
    const unsigned short* xT = (const unsigned short*)(ws + XT_OFF);
    ull* ringAll = (ull*)(ws + RING_OFF);

    __shared__ unsigned short Ah[2][16][136];          // h state, padded stride 272B
    __shared__ unsigned short Xl[2][16][136];          // staged input from prev layer

    for (int i = tid; i < 16 * 136; i += 512) ((unsigned short*)Ah[0])[i] = 0;

    // ---- persistent weight fragments (bf16), identical to R1 ------------
    short8 wh[4][4];
    short8 wx[4][4];
    float  bias_q[4];
    const int KX = (layer == 0) ? 1 : 4;
    {
        const float *Wih, *Whh, *bih, *bhh;
        int kin;
        if (layer == 0) { Wih = Wih0; Whh = Whh0; bih = bih0; bhh = bhh0; kin = 32; }
        else {
            Wih = Wih123 + (size_t)(layer - 1) * 512 * 128;
            Whh = Whh123 + (size_t)(layer - 1) * 512 * 128;
            bih = bih123 + (size_t)(layer - 1) * 512;
            bhh = bhh123 + (size_t)(layer - 1) * 512;
            kin = 128;
        }
#pragma unroll
        for (int q = 0; q < 4; q++) {
            int row = q * 128 + wv * 16 + col;
            bias_q[q] = bih[row] + bhh[row];
#pragma unroll
            for (int kt = 0; kt < 4; kt++) {
                const float* ph = Whh + (size_t)row * 128 + kt * 32 + quad * 8;
                short8 v;
#pragma unroll
                for (int j = 0; j < 8; j++) v[j] = (short)bf16rne(ph[j]);
                wh[kt][q] = v;   // [kt][q] ordering irrelevant, fixed below
            }
        }
        // fix ordering: reload into [q][kt] layout (cheap, registers)
        // (kept simple: redo loop with correct indexing)
#pragma unroll
        for (int q = 0; q < 4; q++) {
            int row = q * 128 + wv * 16 + col;
#pragma unroll
            for (int kt = 0; kt < 4; kt++) {
                const float* ph = Whh + (size_t)row * 128 + kt * 32 + quad * 8;
                short8 v;
#pragma unroll
                for (int j = 0; j < 8; j++) v[j] = (short)bf16rne(ph[j]);
                wh[q][kt] = v;
            }
#pragma unroll
            for (int kt = 0; kt < 4; kt++) {
                short8 v = {0, 0, 0, 0, 0, 0, 0, 0};
                if (kt < KX) {
                    const float* px = Wih + (size_t)row * kin + kt * 32 + quad * 8;
#pragma unroll
                    for (int j = 0; j < 8; j++) v[j] = (short)bf16rne(px[j]);
                }
                wx[q][kt] = v;
            }
        }
    }

    unsigned* myflag   = &flags[layer * 32 + grp];
    unsigned* prevflag = &flags[(layer > 0 ? layer - 1 : 0) * 32 + grp];
    unsigned* mycons   = &cons[(layer > 0 ? layer - 1 : 0) * 32 + grp];
    unsigned* nextcons = &cons[layer * 32 + grp];
    ull* prodRing = ringAll + ((size_t)layer * 32 + grp) * RING_QW_PER_GRP;              // layer<3
    ull* consRing = ringAll + ((size_t)(layer > 0 ? layer - 1 : 0) * 32 + grp) * RING_QW_PER_GRP;

    const int cb = tid >> 5;       // staging row b (0..15)
    const int ck = tid & 31;       // qword within row (k4 = ck*4)

    // ---- prologue -------------------------------------------------------
    if (layer > 0) {
        if (tid == 0) {
            while (__hip_atomic_load(prevflag, __ATOMIC_RELAXED, __HIP_MEMORY_SCOPE_AGENT) < 2u) {}
        }
        __syncthreads();           // flag>=2: h[0],h[1] visible in ring
        ull d0 = __hip_atomic_load(consRing + (size_t)cb * 32 + ck,
                                   __ATOMIC_RELAXED, __HIP_MEMORY_SCOPE_AGENT);
        *(ull*)&Xl[0][cb][ck * 4] = d0;
    }
    short8 axc = {0, 0, 0, 0, 0, 0, 0, 0};
    if (layer == 0)
        axc = *(const short8*)(xT + ((size_t)0 * 512 + b0 + col) * 32 + quad * 8);
    __syncthreads();               // Ah zeros + Xl[0] visible

    float c4[4] = {0.f, 0.f, 0.f, 0.f};
    const int hcol = wv * 16 + col;

    for (int t = 0; t < T_; ++t) {
        const int rb = t & 1;
        // ---- top: control + prefetch (latency overlapped with compute) --
        if (tid == 0 && layer > 0)
            __hip_atomic_store(mycons, (unsigned)(t + 1), __ATOMIC_RELAXED, __HIP_MEMORY_SCOPE_AGENT);
        unsigned pf = 0xffffffffu, pc = 0xffffffffu;
        if (tid == 0) {            // early poll issue; checked at bottom
            if (layer > 0 && t + 2 < T_)
                pf = __hip_atomic_load(prevflag, __ATOMIC_RELAXED, __HIP_MEMORY_SCOPE_AGENT);
            if (layer < 3 && t >= 64)
                pc = __hip_atomic_load(nextcons, __ATOMIC_RELAXED, __HIP_MEMORY_SCOPE_AGENT);
        }
        // producer: copy h[t-1] (transposed via Ah) into MALL ring
        if (layer < 3 && t > 0) {
            ull hv = *(const ull*)&Ah[rb][cb][ck * 4];
            __hip_atomic_store(prodRing + (size_t)((t - 1) & (RING - 1)) * 512 + cb * 32 + ck,
                               hv, __ATOMIC_RELAXED, __HIP_MEMORY_SCOPE_AGENT);
        }
        // consumer: prefetch h[t+1] from ring (safe: flag >= t+2 verified last step)
        ull dn = 0;
        if (layer > 0 && t + 1 < T_)
            dn = __hip_atomic_load(consRing + (size_t)((t + 1) & (RING - 1)) * 512 + cb * 32 + ck,
                                   __ATOMIC_RELAXED, __HIP_MEMORY_SCOPE_AGENT);
        // layer0: x prefetch for t+1
        short8 axn = {0, 0, 0, 0, 0, 0, 0, 0};
        if (layer == 0 && t + 1 < T_)
            axn = *(const short8*)(xT + ((size_t)(t + 1) * 512 + b0 + col) * 32 + quad * 8);

        // ---- A fragments ------------------------------------------------
        short8 ah[4];
        {
            const unsigned short* base = &Ah[rb][col][quad * 8];
#pragma unroll
            for (int kt = 0; kt < 4; kt++) ah[kt] = *(const short8*)(base + kt * 32);
        }
        short8 axf[4];
        if (layer > 0) {
            const unsigned short* base = &Xl[rb][col][quad * 8];
#pragma unroll
            for (int kt = 0; kt < 4; kt++) axf[kt] = *(const short8*)(base + kt * 32);
        }
        floatx4 acc[4];
#pragma unroll
        for (int q = 0; q < 4; q++) {
            float bq = bias_q[q];
            floatx4 a = {bq, bq, bq, bq};
            acc[q] = a;
        }
#pragma unroll
        for (int kt = 0; kt < 4; kt++)
#pragma unroll
            for (int q = 0; q < 4; q++)
                acc[q] = __builtin_amdgcn_mfma_f32_16x16x32_bf16(ah[kt], wh[q][kt], acc[q], 0, 0, 0);
        if (layer == 0) {
#pragma unroll
            for (int q = 0; q < 4; q++)
                acc[q] = __builtin_amdgcn_mfma_f32_16x16x32_bf16(axc, wx[q][0], acc[q], 0, 0, 0);
        } else {
#pragma unroll
            for (int kt = 0; kt < 4; kt++)
#pragma unroll
                for (int q = 0; q < 4; q++)
                    acc[q] = __builtin_amdgcn_mfma_f32_16x16x32_bf16(axf[kt], wx[q][kt], acc[q], 0, 0, 0);
        }
        // ---- gates + state update (verified mapping from R1) ------------
#pragma unroll
        for (int r = 0; r < 4; r++) {
            float iv = sigm(acc[0][r]);
            float fv = sigm(acc[1][r]);
            float gv = tanh_(acc[2][r]);
            float ov = sigm(acc[3][r]);
            float cv = fv * c4[r] + iv * gv;
            c4[r] = cv;
            float hv = ov * tanh_(cv);
            unsigned short hb = bf16rne(hv);
            int m = quad * 4 + r;
            Ah[1 - rb][m][hcol] = hb;
            if (t == T_ - 1)
                hN[((size_t)layer * 512 + b0 + m) * 128 + hcol] = hb;
        }
        // ---- stage next input -------------------------------------------
        if (layer > 0 && t + 1 < T_)
            *(ull*)&Xl[1 - rb][cb][ck * 4] = dn;
        // ---- spin-verify (steady state: first check passes) -------------
        if (tid == 0) {
            if (layer > 0 && t + 2 < T_) {
                unsigned tgt = (unsigned)(t + 3);
                if (pf < tgt)
                    while (__hip_atomic_load(prevflag, __ATOMIC_RELAXED, __HIP_MEMORY_SCOPE_AGENT) < tgt) {}
            }
            if (layer < 3 && t >= 64) {
                unsigned tgt = (unsigned)(t - 63);
                if (pc < tgt)
                    while (__hip_atomic_load(nextcons, __ATOMIC_RELAXED, __HIP_MEMORY_SCOPE_AGENT) < tgt) {}
            }
        }
        __syncthreads();           // drains vmcnt(0): ring stores of h[t-1] acked at MALL
        if (tid == 0 && layer < 3)
            __hip_atomic_store(myflag, (unsigned)t, __ATOMIC_RELAXED, __HIP_MEMORY_SCOPE_AGENT);
        if (layer == 0) axc = axn;
    }
    // ---- epilogue: publish h[911] ---------------------------------------
    if (layer < 3) {
        ull hv = *(const ull*)&Ah[0][cb][ck * 4];   // h[911] lives in parity 0
        __hip_atomic_store(prodRing + (size_t)(911 & (RING - 1)) * 512 + cb * 32 + ck,
                           hv, __ATOMIC_RELAXED, __HIP_MEMORY_SCOPE_AGENT);
        __syncthreads();           // vmcnt(0) drain
        if (tid == 0)
            __hip_atomic_store(myflag, 912u, __ATOMIC_RELAXED, __HIP_MEMORY_SCOPE_AGENT);
    }
}

// ---------------------------------------------------------------------------
// heads: hN [4][512][128] bf16 -> opt/tp/sl/lot, each [4][512][4] fp32
__global__ __launch_bounds__(256) void heads(
    const unsigned short* __restrict__ hN,
    const float* __restrict__ Wopt, const float* __restrict__ bopt,
    const float* __restrict__ Wlot, const float* __restrict__ blot,
    const float* __restrict__ Wtp,  const float* __restrict__ btp,
    const float* __restrict__ Wsl,  const float* __restrict__ bsl,
    float* __restrict__ out) {
    int tid = blockIdx.x * 256 + threadIdx.x;
    if (tid >= 4 * 4 * 512) return;
    int b  = tid & 511;
    int l  = (tid >> 9) & 3;
    int hd = tid >> 11;
    const float *W, *bb;
    if      (hd == 0) { W = Wopt; bb = bopt; }
    else if (hd == 1) { W = Wtp;  bb = btp;  }
    else if (hd == 2) { W = Wsl;  bb = bsl;  }
    else              { W = Wlot; bb = blot; }
    const unsigned short* h = hN + ((size_t)l * 512 + b) * 128;
    float z0 = bb[0], z1 = bb[1], z2 = bb[2], z3 = bb[3];
    for (int i = 0; i < 128; i++) {
        float hv = bf16tof(h[i]);
        z0 += hv * W[0 * 128 + i];
        z1 += hv * W[1 * 128 + i];
        z2 += hv * W[2 * 128 + i];
        z3 += hv * W[3 * 128 + i];
    }
    float o0, o1, o2, o3;
    if (hd == 0) {
        float m = fmaxf(fmaxf(z0, z1), fmaxf(z2, z3));
        float e0 = __builtin_amdgcn_exp2f((z0 - m) * 1.44269504f);
        float e1 = __builtin_amdgcn_exp2f((z1 - m) * 1.44269504f);
        float e2 = __builtin_amdgcn_exp2f((z2 - m) * 1.44269504f);
        float e3 = __builtin_amdgcn_exp2f((z3 - m) * 1.44269504f);
        float rs = __builtin_amdgcn_rcpf(e0 + e1 + e2 + e3);
        float p0 = e0 * rs, p1 = e1 * rs, p2 = e2 * rs, p3 = e3 * rs;
        float m2 = fmaxf(fmaxf(p0, p1), fmaxf(p2, p3));
        float f0 = __builtin_amdgcn_exp2f((p0 - m2) * 1.44269504f);
        float f1 = __builtin_amdgcn_exp2f((p1 - m2) * 1.44269504f);
        float f2 = __builtin_amdgcn_exp2f((p2 - m2) * 1.44269504f);
        float f3 = __builtin_amdgcn_exp2f((p3 - m2) * 1.44269504f);
        float rs2 = __builtin_amdgcn_rcpf(f0 + f1 + f2 + f3);
        o0 = f0 * rs2; o1 = f1 * rs2; o2 = f2 * rs2; o3 = f3 * rs2;
    } else {
        o0 = sigm(sigm(z0)); o1 = sigm(sigm(z1));
        o2 = sigm(sigm(z2)); o3 = sigm(sigm(z3));
    }
    float* o = out + (size_t)hd * 8192 + ((size_t)l * 512 + b) * 4;
    o[0] = o0; o[1] = o1; o[2] = o2; o[3] = o3;
}

// ---------------------------------------------------------------------------
extern "C" void kernel_launch(void* const* d_in, const int* in_sizes, int n_in,
                              void* d_out, int out_size, void* d_ws, size_t ws_size,
                              hipStream_t stream) {
    (void)in_sizes; (void)n_in; (void)out_size; (void)ws_size;
    const float* x      = (const float*)d_in[0];
    const float* Wih0   = (const float*)d_in[1];
    const float* Whh0   = (const float*)d_in[2];
    const float* bih0   = (const float*)d_in[3];
    const float* bhh0   = (const float*)d_in[4];
    const float* Wih123 = (const float*)d_in[5];
    const float* Whh123 = (const float*)d_in[6];
    const float* bih123 = (const float*)d_in[7];
    const float* bhh123 = (const float*)d_in[8];
    const float* Wopt = (const float*)d_in[9];
    const float* bopt = (const float*)d_in[10];
    const float* Wlot = (const float*)d_in[11];
    const float* blot = (const float*)d_in[12];
    const float* Wtp  = (const float*)d_in[13];
    const float* btp  = (const float*)d_in[14];
    const float* Wsl  = (const float*)d_in[15];
    const float* bsl  = (const float*)d_in[16];
    char* ws = (char*)d_ws;

    hipMemsetAsync(ws, 0, 1024, stream);               // flags + cons
    xpose<<<(B_ * T_ * 4 + 255) / 256, 256, 0, stream>>>(x, (unsigned short*)(ws + XT_OFF));
    lstm_scan<<<128, 512, 0, stream>>>(Wih0, Whh0, bih0, bhh0,
                                       Wih123, Whh123, bih123, bhh123, ws);
    heads<<<32, 256, 0, stream>>>((const unsigned short*)(ws + HN_OFF),
                                  Wopt, bopt, Wlot, blot, Wtp, btp, Wsl, bsl,
                                  (float*)d_out);
}